// Round 1
// baseline (2597.680 us; speedup 1.0000x reference)
//
#include <hip/hip_runtime.h>
#include <stdint.h>

// Problem constants (from reference)
#define N_VOX    200000
#define C_CH     64
#define K_OFF    27
#define M_PAIRS  100000
#define KM       (K_OFF * M_PAIRS)              // 2,700,000 pairs
#define TILE     128                            // output voxels per block (power of 2 -> o>>7)
#define NT       ((N_VOX + TILE - 1) / TILE)    // 1563 tiles
#define NB       (NT * K_OFF)                   // 42201 (tile,k) buckets
#define OLDS_STRIDE 68                          // padded LDS row stride (floats) to break bank conflicts
#define WBN      (K_OFF * 4096)                 // 110592 weight elems per layer
#define EPS_BN   1e-5f

typedef __attribute__((ext_vector_type(8))) short   short8_t;  // 8 x bf16 (4 VGPRs)
typedef __attribute__((ext_vector_type(4))) float   f32x4;     // MFMA accum
typedef __attribute__((ext_vector_type(4))) unsigned short u16x4;

__device__ __forceinline__ unsigned short f2bf(float f) {
    union { float f; unsigned u; } v; v.f = f;
    unsigned r = v.u + 0x7FFFu + ((v.u >> 16) & 1u);   // RTNE
    return (unsigned short)(r >> 16);
}

// ---------------- prep: x -> bf16, w1/w2 -> bf16 B-fragment layout, BN fold ----------------
// wb layout: [k][t(kstep,2)][s(slice,4)][d(64)][j(8)] bf16, element c = t*32 + s*8 + j.
// B-frag load for (k,t,ntile n): lane reads short8 at ((t*4 + lane>>4)*64 + n*16 + (lane&15)).
__global__ void prep_kernel(const float* __restrict__ x,
                            const float* __restrict__ w1, const float* __restrict__ w2,
                            const float* __restrict__ g1, const float* __restrict__ b1,
                            const float* __restrict__ m1, const float* __restrict__ v1,
                            const float* __restrict__ g2, const float* __restrict__ b2,
                            const float* __restrict__ m2, const float* __restrict__ v2,
                            unsigned short* __restrict__ xb,
                            unsigned short* __restrict__ wb1, unsigned short* __restrict__ wb2,
                            float* __restrict__ sb1, float* __restrict__ sb2)
{
    long i = (long)blockIdx.x * blockDim.x + threadIdx.x;
    const long XBN = (long)N_VOX * C_CH;   // 12.8M
    if (i < XBN) { xb[i] = f2bf(x[i]); return; }
    long j = i - XBN;
    if (j < 2 * WBN) {
        const float* w = (j < WBN) ? w1 : w2;
        unsigned short* wb = (j < WBN) ? wb1 : wb2;
        int o = (int)(j >= WBN ? j - WBN : j);
        int k   = o >> 12;           // / 4096
        int rem = o & 4095;
        int t  = rem >> 11;
        int sl = (rem >> 9) & 3;
        int d  = (rem >> 3) & 63;
        int jj = rem & 7;
        int c  = t * 32 + sl * 8 + jj;
        wb[o] = f2bf(w[k * 4096 + c * 64 + d]);
        return;
    }
    j -= 2 * WBN;
    if (j < 64) {
        float s = g1[j] * rsqrtf(v1[j] + EPS_BN);
        sb1[j] = s; sb1[64 + j] = b1[j] - m1[j] * s;
    } else if (j < 128) {
        int c = (int)j - 64;
        float s = g2[c] * rsqrtf(v2[c] + EPS_BN);
        sb2[c] = s; sb2[64 + c] = b2[c] - m2[c] * s;
    }
}

// ---------------- counting sort of pairs by key = (out_tile * 27 + k) ----------------
__global__ void hist_kernel(const int* __restrict__ out_map, int* __restrict__ cnt) {
    int p = blockIdx.x * 256 + threadIdx.x;
    if (p >= KM) return;
    int k = p / M_PAIRS;
    int o = out_map[p];
    atomicAdd(&cnt[(o >> 7) * K_OFF + k], 1);
}

__global__ void scan_kernel(const int* __restrict__ cnt, int* __restrict__ offs) {
    __shared__ int part[1024];
    int t = threadIdx.x;
    const int SEG = (NB + 1023) / 1024;   // 42
    int beg = t * SEG;
    int s = 0;
    for (int i = 0; i < SEG; ++i) { int idx = beg + i; if (idx < NB) s += cnt[idx]; }
    part[t] = s;
    __syncthreads();
    for (int d = 1; d < 1024; d <<= 1) {
        int v = (t >= d) ? part[t - d] : 0;
        __syncthreads();
        part[t] += v;
        __syncthreads();
    }
    int run = (t > 0) ? part[t - 1] : 0;
    for (int i = 0; i < SEG; ++i) {
        int idx = beg + i;
        if (idx <= NB) offs[idx] = run;
        if (idx < NB) run += cnt[idx];
    }
}

// payload: in_idx (18 bits) | out_local (bits 18..25); dummy pad rows use out_local = TILE
__global__ void scatter_kernel(const int* __restrict__ in_map, const int* __restrict__ out_map,
                               const int* __restrict__ offs, int* __restrict__ cursor,
                               unsigned int* __restrict__ payload)
{
    int p = blockIdx.x * 256 + threadIdx.x;
    if (p >= KM) return;
    int k = p / M_PAIRS;
    int o = out_map[p];
    int key = (o >> 7) * K_OFF + k;
    int pos = offs[key] + atomicAdd(&cursor[key], 1);
    payload[pos] = (unsigned)in_map[p] | ((unsigned)(o & (TILE - 1)) << 18);
}

// ---------------- fused sparse-conv (+BN [+ReLU] [+residual]) ----------------
// One block per 128-voxel output tile. LDS f32 accumulator (stride 68, +1 dummy row).
// For each k-bucket: W_k B-frags in VGPRs; waves take 16-pair chunks; MFMA 16x16x32 bf16;
// D scattered into LDS via atomicAdd (ds_add_f32). Epilogue fuses BN(+relu)(+residual).
template<int LAYER>
__global__ __launch_bounds__(256, 4) void conv_kernel(
    const unsigned short* __restrict__ xin,     // bf16 rows [N][64]
    const unsigned short* __restrict__ wb,      // pre-swizzled bf16 weights
    const unsigned int* __restrict__ payload,
    const int* __restrict__ offs,
    const float* __restrict__ sb,               // [0:64) scale, [64:128) shift
    const float* __restrict__ xres,             // LAYER==1: residual (f32), else unused
    void* __restrict__ outp)                    // LAYER==0: bf16 h; LAYER==1: f32 d_out
{
    __shared__ float olds[(TILE + 1) * OLDS_STRIDE];
    const int tile = blockIdx.x;
    const int tid = threadIdx.x;
    {
        f32x4* o4 = (f32x4*)olds;
        const int n4 = (TILE + 1) * OLDS_STRIDE / 4;   // 2193
        f32x4 z = {0.f, 0.f, 0.f, 0.f};
        for (int i = tid; i < n4; i += 256) o4[i] = z;
    }
    __syncthreads();

    const int lane  = tid & 63;
    const int wid   = tid >> 6;
    const int r     = lane & 15;     // A-row / B-col / D-col within frag
    const int sfour = lane >> 4;     // k-slice group
    const int base  = tile * K_OFF;
    const short8_t z8 = {0,0,0,0,0,0,0,0};

    for (int k = 0; k < K_OFF; ++k) {
        const int cs = offs[base + k];
        const int ce = offs[base + k + 1];
        const int nch = (ce - cs + 15) >> 4;
        if (wid >= nch) continue;

        // B fragments for this k: [kstep][ntile], each lane 8 contiguous-k bf16
        short8_t Bf[2][4];
        const short8_t* wbk = (const short8_t*)(wb + k * 4096);
        #pragma unroll
        for (int t = 0; t < 2; ++t)
            #pragma unroll
            for (int n = 0; n < 4; ++n)
                Bf[t][n] = wbk[(t * 4 + sfour) * 64 + n * 16 + r];

        for (int ch = wid; ch < nch; ch += 4) {
            int pos = cs + ch * 16 + r;
            unsigned pl = (pos < ce) ? payload[pos] : (unsigned)(TILE << 18);
            int iidx = (int)(pl & 0x3FFFFu);
            int oloc = (int)(pl >> 18);

            short8_t A0 = z8, A1 = z8;
            if (pos < ce) {
                const short8_t* xrow = (const short8_t*)(xin + iidx * 64);
                A0 = xrow[sfour];       // channels [sfour*8, +8)
                A1 = xrow[4 + sfour];   // channels 32 + [sfour*8, +8)
            }

            f32x4 acc[4] = {{0,0,0,0},{0,0,0,0},{0,0,0,0},{0,0,0,0}};
            #pragma unroll
            for (int n = 0; n < 4; ++n) {
                acc[n] = __builtin_amdgcn_mfma_f32_16x16x32_bf16(A0, Bf[0][n], acc[n], 0, 0, 0);
                acc[n] = __builtin_amdgcn_mfma_f32_16x16x32_bf16(A1, Bf[1][n], acc[n], 0, 0, 0);
            }

            // D layout: col = lane&15 (channel n*16+r), row = sfour*4 + j
            #pragma unroll
            for (int j = 0; j < 4; ++j) {
                int drow = sfour * 4 + j;
                int ol = __shfl(oloc, drow, 64);   // lane 'drow' (<16) holds that row's out_local
                float* rowp = &olds[ol * OLDS_STRIDE];
                #pragma unroll
                for (int n = 0; n < 4; ++n)
                    atomicAdd(&rowp[n * 16 + r], acc[n][j]);
            }
        }
    }
    __syncthreads();

    // epilogue: BN fold (+relu / +residual+relu), coalesced vectorized write
    const int row0 = tile * TILE;
    int rows = N_VOX - row0; if (rows > TILE) rows = TILE;
    const f32x4* sc4 = (const f32x4*)sb;
    const f32x4* bi4 = (const f32x4*)(sb + 64);
    for (int e4 = tid; e4 < rows * 16; e4 += 256) {
        int row = e4 >> 4, q = e4 & 15;
        f32x4 v = *(const f32x4*)&olds[row * OLDS_STRIDE + q * 4];
        v = v * sc4[q] + bi4[q];
        int g4 = (row0 + row) * 16 + q;
        if (LAYER == 0) {
            u16x4 h;
            #pragma unroll
            for (int ii = 0; ii < 4; ++ii) {
                float f = v[ii] > 0.f ? v[ii] : 0.f;
                h[ii] = f2bf(f);
            }
            ((u16x4*)outp)[g4] = h;
        } else {
            f32x4 xr = ((const f32x4*)xres)[g4];
            v = v + xr;
            #pragma unroll
            for (int ii = 0; ii < 4; ++ii) v[ii] = v[ii] > 0.f ? v[ii] : 0.f;
            ((f32x4*)outp)[g4] = v;
        }
    }
}

// ---------------- launch ----------------
extern "C" void kernel_launch(void* const* d_in, const int* in_sizes, int n_in,
                              void* d_out, int out_size, void* d_ws, size_t ws_size,
                              hipStream_t stream)
{
    const float* x  = (const float*)d_in[0];
    const float* w1 = (const float*)d_in[1];
    const float* w2 = (const float*)d_in[2];
    const float* g1 = (const float*)d_in[3];
    const float* b1 = (const float*)d_in[4];
    const float* m1 = (const float*)d_in[5];
    const float* v1 = (const float*)d_in[6];
    const float* g2 = (const float*)d_in[7];
    const float* b2 = (const float*)d_in[8];
    const float* m2 = (const float*)d_in[9];
    const float* v2 = (const float*)d_in[10];
    const int* in_map  = (const int*)d_in[11];
    const int* out_map = (const int*)d_in[12];

    char* ws = (char*)d_ws;
    size_t off = 0;
    auto alloc = [&](size_t bytes) -> void* {
        void* p = ws + off;
        off = (off + bytes + 255) & ~(size_t)255;
        return p;
    };
    int*            cnt     = (int*)alloc((size_t)NB * 4);
    int*            cursor  = (int*)alloc((size_t)NB * 4);
    int*            offs    = (int*)alloc((size_t)(NB + 1) * 4);
    float*          sb1     = (float*)alloc(128 * 4);
    float*          sb2     = (float*)alloc(128 * 4);
    unsigned short* wb1     = (unsigned short*)alloc((size_t)WBN * 2);
    unsigned short* wb2     = (unsigned short*)alloc((size_t)WBN * 2);
    unsigned int*   payload = (unsigned int*)alloc((size_t)KM * 4);
    unsigned short* xb      = (unsigned short*)alloc((size_t)N_VOX * C_CH * 2);
    unsigned short* hb      = (unsigned short*)alloc((size_t)N_VOX * C_CH * 2);
    // total ~63 MB

    // zero cnt + cursor (contiguous region)
    size_t zlen = (size_t)((char*)cursor - (char*)cnt) + (size_t)NB * 4;
    hipMemsetAsync(cnt, 0, zlen, stream);

    const long TOT = (long)N_VOX * C_CH + 2 * WBN + 128;
    int prep_blocks = (int)((TOT + 255) / 256);
    prep_kernel<<<prep_blocks, 256, 0, stream>>>(x, w1, w2, g1, b1, m1, v1,
                                                 g2, b2, m2, v2, xb, wb1, wb2, sb1, sb2);

    int pair_blocks = (KM + 255) / 256;
    hist_kernel<<<pair_blocks, 256, 0, stream>>>(out_map, cnt);
    scan_kernel<<<1, 1024, 0, stream>>>(cnt, offs);
    scatter_kernel<<<pair_blocks, 256, 0, stream>>>(in_map, out_map, offs, cursor, payload);

    conv_kernel<0><<<NT, 256, 0, stream>>>(xb, wb1, payload, offs, sb1, nullptr, hb);
    conv_kernel<1><<<NT, 256, 0, stream>>>(hb, wb2, payload, offs, sb2, x, d_out);
}